// Round 6
// baseline (79.345 us; speedup 1.0000x reference)
//
#include <hip/hip_runtime.h>
#include <math.h>

#define BB 8
#define HH 16
#define NN 1024
#define TBC 128          // chamfer block size
#define NSC 8            // scan chunks per bh
#define SCH 128          // scan points per chunk (NN / NSC)
#define POWN 8           // own points per thread (block owns all 1024)
#define TBF 1024         // finalize block size

// ws layout (floats):
//   part[(bh*NSC+sc)*NN + i] = osq_i + min over chunk sc of dot-term
//   128 bh * 8 chunks * 1024 i = 1 M floats = 4 MB, coalesced writes,
//   every slot written every iteration, plain stores, no atomics, no init.

// ---------------------------------------------------------------------------
// chamfer: ONLY pass A (reflection-isometry: both chamfer terms equal).
// ROUND-6: halve the LDS broadcast stream again. Cross-round evidence pins
// broadcast ds_read_b128 at ~9 cyc on the per-CU LDS pipe; reads/pair =
// 1/POWN. Round 5 (POWN=4): 256 reads/wave -> LDS ~7.7 us/CU vs 6 us VALU
// floor (LDS still binding). Here TBC=128 / POWN=8 / SCH=128: grid = 1024
// blocks x 2 waves = 2048 waves (2/SIMD, full machine), 128 reads/wave ->
// per-CU LDS ~3.8 us < 6 us VALU floor: VALU-bound. Per 4-read group:
// 112 VALU (28:1 ratio). Indexed LDS loads, no register rotation (round-1
// lesson), no SMEM tricks (round-3/4 lessons). Reflection math, DIST trees,
// and min pairing bit-identical to passing rounds; min over 8 chunks vs 4
// is exact (min associative).
// ---------------------------------------------------------------------------
__global__ __launch_bounds__(TBC) void chamfer_kernel(
    const float* __restrict__ y_pred,
    const float* __restrict__ sp,
    float* __restrict__ ws)
{
    __shared__ __align__(16) float4 pts[SCH];   // 2 KB

    const int blk = blockIdx.x;          // 1024 blocks
    const int bh  = blk >> 3;
    const int sc  = blk & (NSC - 1);
    const int b   = bh >> 4;             // HH = 16
    const int tid = threadIdx.x;

    float pnx = y_pred[bh * 4 + 0];
    float pny = y_pred[bh * 4 + 1];
    float pnz = y_pred[bh * 4 + 2];
    float pd  = y_pred[bh * 4 + 3];
    float inv = 1.0f / sqrtf(pnx * pnx + pny * pny + pnz * pnz);
    pnx *= inv; pny *= inv; pnz *= inv;

    const float* __restrict__ spb = sp + (size_t)b * NN * 3;

    // stage scan chunk: raw samples with squared norm (1 point / thread)
    {
        int j = sc * SCH + tid;
        float x = spb[j * 3 + 0], y = spb[j * 3 + 1], z = spb[j * 3 + 2];
        pts[tid] = make_float4(x, y, z, x * x + y * y + z * z);
    }

    // own points: reflected, pre-scaled by -2 (identical math to rounds 2-5)
    float mx[POWN], my[POWN], mz[POWN], osq[POWN];
#pragma unroll
    for (int u = 0; u < POWN; ++u) {
        int i = u * TBC + tid;
        float x = spb[i * 3 + 0], y = spb[i * 3 + 1], z = spb[i * 3 + 2];
        float proj = x * pnx + y * pny + z * pnz + pd;
        x -= 2.0f * proj * pnx;
        y -= 2.0f * proj * pny;
        z -= 2.0f * proj * pnz;
        osq[u] = x * x + y * y + z * z;
        mx[u] = -2.0f * x; my[u] = -2.0f * y; mz[u] = -2.0f * z;
    }
    __syncthreads();

    float m0[POWN], m1[POWN];
#pragma unroll
    for (int u = 0; u < POWN; ++u) { m0[u] = 3.4e38f; m1[u] = 3.4e38f; }

#define DIST(qq, u) fmaf(mx[u], qq.x, fmaf(my[u], qq.y, fmaf(mz[u], qq.z, qq.w)))
    for (int j = 0; j < SCH; j += 4) {
        float4 q0 = pts[j + 0];
        float4 q1 = pts[j + 1];
        float4 q2 = pts[j + 2];
        float4 q3 = pts[j + 3];
#pragma unroll
        for (int u = 0; u < POWN; ++u) {
            float d0 = DIST(q0, u);
            float d1 = DIST(q1, u);
            float d2 = DIST(q2, u);
            float d3 = DIST(q3, u);
            m0[u] = fminf(fminf(m0[u], d0), d1);   // v_min3_f32
            m1[u] = fminf(fminf(m1[u], d2), d3);
        }
    }
#undef DIST

    // per-own-point chunk partial (osq constant across chunks, so
    // min over chunks of (osq + partial) == osq + overall min)
    float* wp = ws + (size_t)(bh * NSC + sc) * NN;
#pragma unroll
    for (int u = 0; u < POWN; ++u)
        wp[u * TBC + tid] = osq[u] + fminf(m0[u], m1[u]);
}

// ---------------------------------------------------------------------------
// finalize (per batch, 1024 threads): ROUND-6 merges the reduce kernel in,
// saving one launch. Wave w (of 16) owns h=w: lanes read float4-coalesced
// across i, min over the 8 chunk rows per component, fixed-order lane sum +
// shfl tree -> sde. 512 KB/block of L2-hot partials with full MLP (rounds
// 0/1's 8-block slowness was 256 threads + 16-thread strided groups; this
// is 1024 threads, lane-contiguous float4). Centroid, conf, angle-NMS,
// stable rank, write: same logic as rounds 2-5, all fixed-order, no atomics.
// ---------------------------------------------------------------------------
__global__ __launch_bounds__(TBF) void finalize_kernel(
    const float* __restrict__ ws,
    const float* __restrict__ y_pred,
    const float* __restrict__ sp,
    float* __restrict__ out)
{
    const int b   = blockIdx.x;
    const int tid = threadIdx.x;
    const int w   = tid >> 6;            // wave index 0..15
    const int ln  = tid & 63;            // lane

    __shared__ float sde_s[HH], nx_s[HH], ny_s[HH], nz_s[HH], d_s[HH], conf_s[HH];
    __shared__ float wred[16][3];
    __shared__ float cms[3];
    __shared__ int keep_s[HH];

    // centroid: exactly one sample per thread, wave partials, fixed-order
    const float* spb = sp + (size_t)b * NN * 3;
    {
        float sx = spb[tid * 3 + 0];
        float sy = spb[tid * 3 + 1];
        float sz = spb[tid * 3 + 2];
        for (int off = 32; off; off >>= 1) {
            sx += __shfl_down(sx, off, 64);
            sy += __shfl_down(sy, off, 64);
            sz += __shfl_down(sz, off, 64);
        }
        if (ln == 0) { wred[w][0] = sx; wred[w][1] = sy; wred[w][2] = sz; }
    }

    // sde: wave w handles h = w. Lane ln covers float4 indices ln + 64*k.
    {
        const int h = w;
        const float* base = ws + (size_t)((b * HH + h) * NSC) * NN;
        const float4* r0 = (const float4*)(base + 0 * NN);
        const float4* r1 = (const float4*)(base + 1 * NN);
        const float4* r2 = (const float4*)(base + 2 * NN);
        const float4* r3 = (const float4*)(base + 3 * NN);
        const float4* r4 = (const float4*)(base + 4 * NN);
        const float4* r5 = (const float4*)(base + 5 * NN);
        const float4* r6 = (const float4*)(base + 6 * NN);
        const float4* r7 = (const float4*)(base + 7 * NN);
        float acc = 0.0f;
        for (int k = 0; k < 4; ++k) {
            int i4 = ln + 64 * k;
            float4 a0 = r0[i4], a1 = r1[i4], a2 = r2[i4], a3 = r3[i4];
            float4 a4 = r4[i4], a5 = r5[i4], a6 = r6[i4], a7 = r7[i4];
            float e0 = fminf(fminf(fminf(a0.x, a1.x), fminf(a2.x, a3.x)),
                             fminf(fminf(a4.x, a5.x), fminf(a6.x, a7.x)));
            float e1 = fminf(fminf(fminf(a0.y, a1.y), fminf(a2.y, a3.y)),
                             fminf(fminf(a4.y, a5.y), fminf(a6.y, a7.y)));
            float e2 = fminf(fminf(fminf(a0.z, a1.z), fminf(a2.z, a3.z)),
                             fminf(fminf(a4.z, a5.z), fminf(a6.z, a7.z)));
            float e3 = fminf(fminf(fminf(a0.w, a1.w), fminf(a2.w, a3.w)),
                             fminf(fminf(a4.w, a5.w), fminf(a6.w, a7.w)));
            acc += (e0 + e1) + (e2 + e3);
        }
        for (int off = 32; off; off >>= 1) acc += __shfl_down(acc, off, 64);
        if (ln == 0) sde_s[h] = acc;
    }
    __syncthreads();

    if (tid == 0) {
        float X = 0.0f, Y = 0.0f, Z = 0.0f;
        for (int g = 0; g < 16; ++g) {
            X += wred[g][0]; Y += wred[g][1]; Z += wred[g][2];
        }
        cms[0] = X / NN; cms[1] = Y / NN; cms[2] = Z / NN;
    }
    if (tid < HH) {
        int h = tid;
        float nx = y_pred[(b * HH + h) * 4 + 0];
        float ny = y_pred[(b * HH + h) * 4 + 1];
        float nz = y_pred[(b * HH + h) * 4 + 2];
        float d  = y_pred[(b * HH + h) * 4 + 3];
        float inv = 1.0f / sqrtf(nx * nx + ny * ny + nz * nz);
        nx *= inv; ny *= inv; nz *= inv;
        nx_s[h] = nx; ny_s[h] = ny; nz_s[h] = nz; d_s[h] = d;
        // both chamfer terms equal -> 2/N * per-bh sum
        sde_s[h] = sde_s[h] * (2.0f / NN);
    }
    __syncthreads();

    if (tid < HH) {
        int h = tid;
        float mn = sde_s[0], mx = sde_s[0];
        for (int g = 1; g < HH; ++g) {
            mn = fminf(mn, sde_s[g]);
            mx = fmaxf(mx, sde_s[g]);
        }
        float sde  = sde_s[h];
        float conf = 1.0f - (sde - mn) / fabsf(mx - mn);
        conf_s[h]  = conf;
        bool valid = (sde <= 10.0f);
        bool sup   = false;
        if (valid) {
            for (int g = 0; g < HH; ++g) {
                if (g == h) continue;
                float c = nx_s[h] * nx_s[g] + ny_s[h] * ny_s[g] + nz_s[h] * nz_s[g];
                c = fminf(1.0f, fmaxf(-1.0f, c));
                float ang = acosf(c) * 57.29577951308232f;
                bool close = (ang < 30.0f) || (180.0f - ang < 30.0f);
                if (close && (sde_s[g] <= 10.0f) && (sde >= sde_s[g])) sup = true;
            }
        }
        keep_s[h] = (valid && !sup) ? 1 : 0;
    }
    __syncthreads();

    if (tid < HH) {
        int h = tid;
        // stable descending rank on key = keep ? conf : -inf (jnp.argsort(-key))
        float keyh = keep_s[h] ? conf_s[h] : -INFINITY;
        int pos = 0;
        for (int g = 0; g < HH; ++g) {
            float keyg = keep_s[g] ? conf_s[g] : -INFINITY;
            if (keyg > keyh || (keyg == keyh && g < h)) ++pos;
        }
        float cmx = cms[0], cmy = cms[1], cmz = cms[2];
        float nx = nx_s[h], ny = ny_s[h], nz = nz_s[h];
        float t  = nx * cmx + ny * cmy + nz * cmz + d_s[h];
        float px = cmx - t * nx, py = cmy - t * ny, pz = cmz - t * nz;

        float* o = out + (size_t)(b * HH + pos) * 8;
        if (keep_s[h]) {
            o[0] = nx; o[1] = ny; o[2] = nz;
            o[3] = px; o[4] = py; o[5] = pz;
            o[6] = conf_s[h];
            o[7] = sde_s[h];
        } else {
            for (int c = 0; c < 8; ++c) o[c] = 0.0f;
        }
    }
}

extern "C" void kernel_launch(void* const* d_in, const int* in_sizes, int n_in,
                              void* d_out, int out_size, void* d_ws, size_t ws_size,
                              hipStream_t stream) {
    const float* y_pred = (const float*)d_in[0];   // (8,16,4) f32
    const float* sp     = (const float*)d_in[1];   // (8,1024,3) f32
    float* out          = (float*)d_out;           // (8,16,8) f32
    float* ws           = (float*)d_ws;            // 4 MB partials

    chamfer_kernel<<<dim3(BB * HH * NSC), dim3(TBC), 0, stream>>>(y_pred, sp, ws);
    finalize_kernel<<<dim3(BB), dim3(TBF), 0, stream>>>(ws, y_pred, sp, out);
}

// Round 7
// 76.254 us; speedup vs baseline: 1.0405x; 1.0405x over previous
//
#include <hip/hip_runtime.h>
#include <math.h>

#define BB 8
#define HH 16
#define NN 1024
#define TBC 128          // chamfer block size
#define NSC 8            // scan chunks per bh
#define SCH 128          // scan points per chunk (NN / NSC)
#define POWN 8           // own points per thread (block owns all 1024)
#define TB 256           // reduce / finalize block size
#define SUMBASE (BB * HH * NSC * NN)   // 1M floats of partials, then sums

// ws layout (floats):
//   [0, SUMBASE)             part[(bh*NSC+sc)*NN + i] = osq_i + min over
//                            chunk sc of dot-term (4 MB, coalesced writes)
//   [SUMBASE, SUMBASE+128)   per-bh sums from the reduce kernel
// Every slot written every iteration, plain stores, no atomics, no init.

// ---------------------------------------------------------------------------
// chamfer: ONLY pass A (reflection-isometry: both chamfer terms equal).
// ROUND-7: this is round-6's chamfer verbatim (TBC=128 / POWN=8 / SCH=128:
// 128 broadcast ds_read_b128 per wave -> per-CU LDS ~3.8 us, safely under
// the ~6 us VALU floor; 2048 waves = 2/SIMD, full machine). Round 7 is a
// clean A/B: round 6 changed chamfer AND merged the reduce into an 8-block
// finalize simultaneously and regressed; here only the chamfer change is
// kept, reduce/finalize restored to the round-5 champion structure.
// ---------------------------------------------------------------------------
__global__ __launch_bounds__(TBC) void chamfer_kernel(
    const float* __restrict__ y_pred,
    const float* __restrict__ sp,
    float* __restrict__ ws)
{
    __shared__ __align__(16) float4 pts[SCH];   // 2 KB

    const int blk = blockIdx.x;          // 1024 blocks
    const int bh  = blk >> 3;
    const int sc  = blk & (NSC - 1);
    const int b   = bh >> 4;             // HH = 16
    const int tid = threadIdx.x;

    float pnx = y_pred[bh * 4 + 0];
    float pny = y_pred[bh * 4 + 1];
    float pnz = y_pred[bh * 4 + 2];
    float pd  = y_pred[bh * 4 + 3];
    float inv = 1.0f / sqrtf(pnx * pnx + pny * pny + pnz * pnz);
    pnx *= inv; pny *= inv; pnz *= inv;

    const float* __restrict__ spb = sp + (size_t)b * NN * 3;

    // stage scan chunk: raw samples with squared norm (1 point / thread)
    {
        int j = sc * SCH + tid;
        float x = spb[j * 3 + 0], y = spb[j * 3 + 1], z = spb[j * 3 + 2];
        pts[tid] = make_float4(x, y, z, x * x + y * y + z * z);
    }

    // own points: reflected, pre-scaled by -2 (identical math to rounds 2-6)
    float mx[POWN], my[POWN], mz[POWN], osq[POWN];
#pragma unroll
    for (int u = 0; u < POWN; ++u) {
        int i = u * TBC + tid;
        float x = spb[i * 3 + 0], y = spb[i * 3 + 1], z = spb[i * 3 + 2];
        float proj = x * pnx + y * pny + z * pnz + pd;
        x -= 2.0f * proj * pnx;
        y -= 2.0f * proj * pny;
        z -= 2.0f * proj * pnz;
        osq[u] = x * x + y * y + z * z;
        mx[u] = -2.0f * x; my[u] = -2.0f * y; mz[u] = -2.0f * z;
    }
    __syncthreads();

    float m0[POWN], m1[POWN];
#pragma unroll
    for (int u = 0; u < POWN; ++u) { m0[u] = 3.4e38f; m1[u] = 3.4e38f; }

#define DIST(qq, u) fmaf(mx[u], qq.x, fmaf(my[u], qq.y, fmaf(mz[u], qq.z, qq.w)))
    for (int j = 0; j < SCH; j += 4) {
        float4 q0 = pts[j + 0];
        float4 q1 = pts[j + 1];
        float4 q2 = pts[j + 2];
        float4 q3 = pts[j + 3];
#pragma unroll
        for (int u = 0; u < POWN; ++u) {
            float d0 = DIST(q0, u);
            float d1 = DIST(q1, u);
            float d2 = DIST(q2, u);
            float d3 = DIST(q3, u);
            m0[u] = fminf(fminf(m0[u], d0), d1);   // v_min3_f32
            m1[u] = fminf(fminf(m1[u], d2), d3);
        }
    }
#undef DIST

    // per-own-point chunk partial (osq constant across chunks, so
    // min over chunks of (osq + partial) == osq + overall min)
    float* wp = ws + (size_t)(bh * NSC + sc) * NN;
#pragma unroll
    for (int u = 0; u < POWN; ++u)
        wp[u * TBC + tid] = osq[u] + fminf(m0[u], m1[u]);
}

// ---------------------------------------------------------------------------
// reduce: 128 blocks (one per bh), 256 threads — round-5 structure, adapted
// to NSC=8 rows. Thread t reads float4 #t of each of the 8 chunk rows
// (perfectly coalesced: row = 256 float4 = 256 lanes), min across chunks
// per component, sums its 4 components, then a deterministic block sum
// (shfl tree + fixed-order 4-wave combine) -> ONE float per bh. 4 MB total
// spread over 128 CUs in parallel (round-6's merged version choked this
// through 8 blocks).
// ---------------------------------------------------------------------------
__global__ __launch_bounds__(TB) void reduce_kernel(
    const float* __restrict__ ws_in,
    float* __restrict__ ws_out)
{
    __shared__ float wsum[4];
    const int bh  = blockIdx.x;
    const int tid = threadIdx.x;

    const float* base = ws_in + (size_t)(bh * NSC) * NN;
    const float4* r0 = (const float4*)(base + 0 * NN);
    const float4* r1 = (const float4*)(base + 1 * NN);
    const float4* r2 = (const float4*)(base + 2 * NN);
    const float4* r3 = (const float4*)(base + 3 * NN);
    const float4* r4 = (const float4*)(base + 4 * NN);
    const float4* r5 = (const float4*)(base + 5 * NN);
    const float4* r6 = (const float4*)(base + 6 * NN);
    const float4* r7 = (const float4*)(base + 7 * NN);

    float4 a0 = r0[tid], a1 = r1[tid], a2 = r2[tid], a3 = r3[tid];
    float4 a4 = r4[tid], a5 = r5[tid], a6 = r6[tid], a7 = r7[tid];
    float e0 = fminf(fminf(fminf(a0.x, a1.x), fminf(a2.x, a3.x)),
                     fminf(fminf(a4.x, a5.x), fminf(a6.x, a7.x)));
    float e1 = fminf(fminf(fminf(a0.y, a1.y), fminf(a2.y, a3.y)),
                     fminf(fminf(a4.y, a5.y), fminf(a6.y, a7.y)));
    float e2 = fminf(fminf(fminf(a0.z, a1.z), fminf(a2.z, a3.z)),
                     fminf(fminf(a4.z, a5.z), fminf(a6.z, a7.z)));
    float e3 = fminf(fminf(fminf(a0.w, a1.w), fminf(a2.w, a3.w)),
                     fminf(fminf(a4.w, a5.w), fminf(a6.w, a7.w)));
    float s  = (e0 + e1) + (e2 + e3);

    for (int off = 32; off; off >>= 1) s += __shfl_down(s, off, 64);
    if ((tid & 63) == 0) wsum[tid >> 6] = s;
    __syncthreads();
    if (tid == 0)
        ws_out[SUMBASE + bh] = (wsum[0] + wsum[1]) + (wsum[2] + wsum[3]);
}

// ---------------------------------------------------------------------------
// finalize (per batch, 256 threads): centroid; sde[h] = 2/N * per-bh sum;
// conf; angle-NMS; stable rank; write. Verbatim round 5.
// ---------------------------------------------------------------------------
__global__ __launch_bounds__(TB) void finalize_kernel(
    const float* __restrict__ ws,
    const float* __restrict__ y_pred,
    const float* __restrict__ sp,
    float* __restrict__ out)
{
    const int b   = blockIdx.x;
    const int tid = threadIdx.x;

    __shared__ float sde_s[HH], nx_s[HH], ny_s[HH], nz_s[HH], d_s[HH], conf_s[HH];
    __shared__ float cmacc[3];
    __shared__ int keep_s[HH];

    if (tid < 3) cmacc[tid] = 0.0f;
    __syncthreads();

    // centroid: 1024 samples over 256 threads
    const float* spb = sp + (size_t)b * NN * 3;
    float sx = 0.0f, sy = 0.0f, sz = 0.0f;
    for (int p = tid; p < NN; p += TB) {
        sx += spb[p * 3 + 0];
        sy += spb[p * 3 + 1];
        sz += spb[p * 3 + 2];
    }
    for (int off = 32; off; off >>= 1) {
        sx += __shfl_down(sx, off, 64);
        sy += __shfl_down(sy, off, 64);
        sz += __shfl_down(sz, off, 64);
    }
    if ((tid & 63) == 0) {
        atomicAdd(&cmacc[0], sx);
        atomicAdd(&cmacc[1], sy);
        atomicAdd(&cmacc[2], sz);
    }
    __syncthreads();

    const float cmx = cmacc[0] / NN, cmy = cmacc[1] / NN, cmz = cmacc[2] / NN;

    if (tid < HH) {
        int h = tid;
        float nx = y_pred[(b * HH + h) * 4 + 0];
        float ny = y_pred[(b * HH + h) * 4 + 1];
        float nz = y_pred[(b * HH + h) * 4 + 2];
        float d  = y_pred[(b * HH + h) * 4 + 3];
        float inv = 1.0f / sqrtf(nx * nx + ny * ny + nz * nz);
        nx *= inv; ny *= inv; nz *= inv;
        nx_s[h] = nx; ny_s[h] = ny; nz_s[h] = nz; d_s[h] = d;
        // both chamfer terms equal -> 2/N * per-bh sum
        sde_s[h] = ws[SUMBASE + b * HH + h] * (2.0f / NN);
    }
    __syncthreads();

    if (tid < HH) {
        int h = tid;
        float mn = sde_s[0], mx = sde_s[0];
        for (int g = 1; g < HH; ++g) {
            mn = fminf(mn, sde_s[g]);
            mx = fmaxf(mx, sde_s[g]);
        }
        float sde  = sde_s[h];
        float conf = 1.0f - (sde - mn) / fabsf(mx - mn);
        conf_s[h]  = conf;
        bool valid = (sde <= 10.0f);
        bool sup   = false;
        if (valid) {
            for (int g = 0; g < HH; ++g) {
                if (g == h) continue;
                float c = nx_s[h] * nx_s[g] + ny_s[h] * ny_s[g] + nz_s[h] * nz_s[g];
                c = fminf(1.0f, fmaxf(-1.0f, c));
                float ang = acosf(c) * 57.29577951308232f;
                bool close = (ang < 30.0f) || (180.0f - ang < 30.0f);
                if (close && (sde_s[g] <= 10.0f) && (sde >= sde_s[g])) sup = true;
            }
        }
        keep_s[h] = (valid && !sup) ? 1 : 0;
    }
    __syncthreads();

    if (tid < HH) {
        int h = tid;
        // stable descending rank on key = keep ? conf : -inf (jnp.argsort(-key))
        float keyh = keep_s[h] ? conf_s[h] : -INFINITY;
        int pos = 0;
        for (int g = 0; g < HH; ++g) {
            float keyg = keep_s[g] ? conf_s[g] : -INFINITY;
            if (keyg > keyh || (keyg == keyh && g < h)) ++pos;
        }
        float nx = nx_s[h], ny = ny_s[h], nz = nz_s[h];
        float t  = nx * cmx + ny * cmy + nz * cmz + d_s[h];
        float px = cmx - t * nx, py = cmy - t * ny, pz = cmz - t * nz;

        float* o = out + (size_t)(b * HH + pos) * 8;
        if (keep_s[h]) {
            o[0] = nx; o[1] = ny; o[2] = nz;
            o[3] = px; o[4] = py; o[5] = pz;
            o[6] = conf_s[h];
            o[7] = sde_s[h];
        } else {
            for (int c = 0; c < 8; ++c) o[c] = 0.0f;
        }
    }
}

extern "C" void kernel_launch(void* const* d_in, const int* in_sizes, int n_in,
                              void* d_out, int out_size, void* d_ws, size_t ws_size,
                              hipStream_t stream) {
    const float* y_pred = (const float*)d_in[0];   // (8,16,4) f32
    const float* sp     = (const float*)d_in[1];   // (8,1024,3) f32
    float* out          = (float*)d_out;           // (8,16,8) f32
    float* ws           = (float*)d_ws;            // 4 MB partials + 128 sums

    chamfer_kernel<<<dim3(BB * HH * NSC), dim3(TBC), 0, stream>>>(y_pred, sp, ws);
    reduce_kernel<<<dim3(BB * HH), dim3(TB), 0, stream>>>(ws, ws);
    finalize_kernel<<<dim3(BB), dim3(TB), 0, stream>>>(ws, y_pred, sp, out);
}